// Round 2
// baseline (379.385 us; speedup 1.0000x reference)
//
#include <hip/hip_runtime.h>
#include <hip/hip_cooperative_groups.h>
#include <cstdint>
#include <math.h>

namespace cg = cooperative_groups;

#define HH 2048
#define WW 2048
#define HWPX (HH*WW)
#define NSEG 10
#define NB 128
#define HIST_WORDS (NSEG*NB)       // 1280
#define LOWR 0.03125f
#define INV_LOWW 4096.0f           // NB / LOWR
#define BINW (LOWR/(float)NB)

// One cooperative kernel: 512 blocks x 256 = 2 blocks/CU, all co-resident.
// NBLK MUST stay 512: the phase-2 accumulation order (and thus the bit-exact
// absmax, currently at 0.015625) depends on the grid-stride mapping.
#define NBLK 512
#define NTHR 256
#define NTH (NBLK*NTHR)            // 131072 threads
#define SLICE_W 1320               // 1280 hist + 40 acc per block
#define NPART 16                   // reduce fan-in stage (512/16 = 32 slices each)

// workspace layout (32-bit words) — everything written before read inside the
// single launch (harness 0xAA poison harmless).
#define WS_BMM 0                            // 1024: per-block min[512], max[512]
#define WS_PART 1024                        // NPART * SLICE_W = 21120 partials
#define WS_DSEG 22144                       // 16B-aligned: 11 float4 (seg 10 = zeros)
#define WS_DMM (WS_DSEG + 44)               // (fallback path only)
#define WS_DVAL 22192                       // HWPX floats: dval staged P2 -> P5 (16.8 MB)
#define WS_SLICE (WS_DVAL + HWPX)           // NBLK * SLICE_W (2.7 MB)

typedef float vfloat4 __attribute__((ext_vector_type(4)));

// bins = linspace(dmin,dmax,11); pixel in seg s iff bins[s] <= v < bins[s+1].
// v == dmax is in NO segment -> 10 (maps to zero D).
__device__ __forceinline__ int seg_of(float v, float dmin, float dmax, float invw) {
    int sg = (int)((v - dmin) * invw);
    sg = sg > (NSEG-1) ? (NSEG-1) : sg;
    return (v >= dmax) ? NSEG : sg;
}

// Re-reduce the 512+512 per-block min/max values (4 KB, L2-hot after P1).
__device__ __forceinline__ void block_minmax(const float* wsf, float& dmin, float& dmax,
                                             float smn[4], float smx[4]) {
    float v0 = fminf(wsf[WS_BMM + threadIdx.x], wsf[WS_BMM + 256 + threadIdx.x]);
    float v1 = fmaxf(wsf[WS_BMM + NBLK + threadIdx.x],
                     wsf[WS_BMM + NBLK + 256 + threadIdx.x]);
    #pragma unroll
    for (int off = 32; off > 0; off >>= 1) {
        v0 = fminf(v0, __shfl_down(v0, off, 64));
        v1 = fmaxf(v1, __shfl_down(v1, off, 64));
    }
    int wid = threadIdx.x >> 6;
    if ((threadIdx.x & 63) == 0) { smn[wid] = v0; smx[wid] = v1; }
    __syncthreads();
    dmin = fminf(fminf(smn[0], smn[1]), fminf(smn[2], smn[3]));
    dmax = fmaxf(fmaxf(smx[0], smx[1]), fmaxf(smx[2], smx[3]));
}

// ---------------------------------------------------------------------------
// Fused cooperative kernel. Phases (bit-identical math to the 5-kernel chain):
//   P1 minmax -> sync -> P2 hist/sums/dval -> sync -> P3 slice reduce (96 blk)
//   -> sync -> P4 stats (block 0) -> sync -> P5 smoothing + output.
// L2 plan: a block re-reads ITS OWN depth/dval slice in P2/P5 (same resident
// block => same XCD L2 => hit). Image is nt-loaded (streaming, don't evict).
// dval is a PLAIN store (stays dirty in producer's L2 for P5). Halo rows and
// cross-block stats ride the 256 MB Infinity Cache.
// ---------------------------------------------------------------------------
__global__ __launch_bounds__(256, 2) void fused_eigm(const float* __restrict__ image,
                                                     const float* __restrict__ depth,
                                                     const float* __restrict__ mu0p,
                                                     const float* __restrict__ mu1p,
                                                     const float* __restrict__ mu2p,
                                                     uint32_t* __restrict__ wsu,
                                                     float* __restrict__ out) {
    cg::grid_group grid = cg::this_grid();
    __shared__ uint32_t s_hist[HIST_WORDS];
    __shared__ float s_red[4][40];
    __shared__ float s_acc[40];
    __shared__ float smn[4], smx[4];
    __shared__ float4 s_D4[NSEG+1];
    float* wsf = (float*)wsu;
    const int tid = blockIdx.x * NTHR + threadIdx.x;

    // ---- P1: per-block depth min/max (fills this block's L2 slice) ----
    {
        float vmin = INFINITY, vmax = 0.0f;
        const float4* d4 = (const float4*)depth;
        for (int i = tid; i < HWPX/4; i += NTH) {
            float4 v = d4[i];
            vmin = fminf(vmin, fminf(fminf(v.x, v.y), fminf(v.z, v.w)));
            vmax = fmaxf(vmax, fmaxf(fmaxf(v.x, v.y), fmaxf(v.z, v.w)));
        }
        #pragma unroll
        for (int off = 32; off > 0; off >>= 1) {
            vmin = fminf(vmin, __shfl_down(vmin, off, 64));
            vmax = fmaxf(vmax, __shfl_down(vmax, off, 64));
        }
        int wid = threadIdx.x >> 6;
        if ((threadIdx.x & 63) == 0) { smn[wid] = vmin; smx[wid] = vmax; }
        __syncthreads();
        if (threadIdx.x == 0) {
            wsf[WS_BMM + blockIdx.x]        = fminf(fminf(smn[0], smn[1]), fminf(smn[2], smn[3]));
            wsf[WS_BMM + NBLK + blockIdx.x] = fmaxf(fmaxf(smx[0], smx[1]), fmaxf(smx[2], smx[3]));
        }
        __syncthreads();                       // smn/smx reused below
    }
    grid.sync();                               // s1

    // ---- global min/max (redundant per block), kept in registers to P5 ----
    for (int j = threadIdx.x; j < HIST_WORDS; j += 256) s_hist[j] = 0;
    float dmin, dmax;
    block_minmax(wsf, dmin, dmax, smn, smx);   // __syncthreads inside covers s_hist
    float invw = 10.0f / (dmax - dmin);

    // ---- P2: register per-seg stats; LDS hist for m < LOWR; dval staged ----
    {
        float mu0 = *mu0p, mu1 = *mu1p, mu2 = *mu2p;
        float c_cnt[NSEG], c_r[NSEG], c_g[NSEG], c_b[NSEG];
        #pragma unroll
        for (int s = 0; s < NSEG; ++s) { c_cnt[s]=0.f; c_r[s]=0.f; c_g[s]=0.f; c_b[s]=0.f; }

        const vfloat4* r4 = (const vfloat4*)image;
        const vfloat4* g4 = (const vfloat4*)(image + HWPX);
        const vfloat4* b4 = (const vfloat4*)(image + 2*HWPX);
        const float4* d4 = (const float4*)depth;
        vfloat4* dval4 = (vfloat4*)(wsf + WS_DVAL);
        for (int i = tid; i < HWPX/4; i += NTH) {
            vfloat4 rv = __builtin_nontemporal_load(&r4[i]);   // image: stream, don't evict
            vfloat4 gv = __builtin_nontemporal_load(&g4[i]);
            vfloat4 bv = __builtin_nontemporal_load(&b4[i]);
            float4 dv = d4[i];                                 // depth: L2-hot from P1
            float ra[4] = {rv.x, rv.y, rv.z, rv.w};
            float ga[4] = {gv.x, gv.y, gv.z, gv.w};
            float ba[4] = {bv.x, bv.y, bv.z, bv.w};
            float da[4] = {dv.x, dv.y, dv.z, dv.w};
            float dvo[4];
            #pragma unroll
            for (int j = 0; j < 4; ++j) {
                int sg = seg_of(da[j], dmin, dmax, invw);
                float m = fminf(ra[j], fminf(ga[j], ba[j]));
                if (sg < NSEG && m < LOWR) {
                    atomicAdd(&s_hist[sg*NB + (int)(m * INV_LOWW)], 1u);
                }
                #pragma unroll
                for (int s = 0; s < NSEG; ++s) {
                    float sel = (sg == s) ? 1.0f : 0.0f;
                    c_cnt[s] += sel;
                    c_r[s] += sel * ra[j];
                    c_g[s] += sel * ga[j];
                    c_b[s] += sel * ba[j];
                }
                dvo[j] = mu0 + mu1 * fmaxf(ga[j], ba[j]) + mu2 * ra[j];
            }
            vfloat4 dq = {dvo[0], dvo[1], dvo[2], dvo[3]};
            dval4[i] = dq;                     // PLAIN store: keep in this XCD's L2 for P5
        }
        #pragma unroll
        for (int s = 0; s < NSEG; ++s) {
            #pragma unroll
            for (int off = 32; off > 0; off >>= 1) {
                c_cnt[s] += __shfl_down(c_cnt[s], off, 64);
                c_r[s]   += __shfl_down(c_r[s],   off, 64);
                c_g[s]   += __shfl_down(c_g[s],   off, 64);
                c_b[s]   += __shfl_down(c_b[s],   off, 64);
            }
        }
        int wid = threadIdx.x >> 6;
        if ((threadIdx.x & 63) == 0) {
            #pragma unroll
            for (int s = 0; s < NSEG; ++s) {
                s_red[wid][s]      = c_cnt[s];
                s_red[wid][10 + s] = c_r[s];
                s_red[wid][20 + s] = c_g[s];
                s_red[wid][30 + s] = c_b[s];
            }
        }
        __syncthreads();
        uint32_t* slice = wsu + WS_SLICE + (size_t)blockIdx.x * SLICE_W;
        for (int j = threadIdx.x; j < HIST_WORDS; j += 256)
            __builtin_nontemporal_store(s_hist[j], &slice[j]);
        if (threadIdx.x < 40) {
            float v = s_red[0][threadIdx.x] + s_red[1][threadIdx.x]
                    + s_red[2][threadIdx.x] + s_red[3][threadIdx.x];
            __builtin_nontemporal_store(v, &((float*)slice)[HIST_WORDS + threadIdx.x]);
        }
    }
    grid.sync();                               // s2

    // ---- P3: reduce NBLK slices -> NPART partials (96 working blocks) ----
    if (blockIdx.x < 6*NPART) {
        int jx = (blockIdx.x % 6) * 256 + threadIdx.x;
        int y  = blockIdx.x / 6;
        if (jx < SLICE_W) {
            const uint32_t* p = wsu + WS_SLICE + (size_t)(y * (NBLK/NPART)) * SLICE_W + jx;
            if (jx < HIST_WORDS) {
                uint32_t acc = 0;
                #pragma unroll 4
                for (int b = 0; b < NBLK/NPART; ++b) acc += p[(size_t)b * SLICE_W];
                wsu[WS_PART + y*SLICE_W + jx] = acc;
            } else {
                float acc = 0.0f;
                #pragma unroll 4
                for (int b = 0; b < NBLK/NPART; ++b) acc += ((const float*)p)[(size_t)b * SLICE_W];
                ((float*)wsu)[WS_PART + y*SLICE_W + jx] = acc;
            }
        }
    }
    grid.sync();                               // s3

    // ---- P4: final partial sum + bottom-k scan + D_seg (block 0 only) ----
    if (blockIdx.x == 0) {
        for (int j = threadIdx.x; j < SLICE_W; j += 256) {
            if (j < HIST_WORDS) {
                uint32_t acc = 0;
                #pragma unroll
                for (int y = 0; y < NPART; ++y) acc += wsu[WS_PART + y*SLICE_W + j];
                s_hist[j] = acc;
            } else {
                float acc = 0.0f;
                #pragma unroll
                for (int y = 0; y < NPART; ++y) acc += wsf[WS_PART + y*SLICE_W + j];
                s_acc[j - HIST_WORDS] = acc;
            }
        }
        __syncthreads();
        int s = threadIdx.x;
        if (s < NSEG) {
            float fn = s_acc[s];               // exact integer-valued float
            uint32_t n = (uint32_t)(fn + 0.5f);
            uint32_t k = n / 100;              // n * BOTTOM_PCT // 100
            const uint32_t* h = &s_hist[s*NB];
            float bsum = 0.0f; uint32_t taken = 0;
            for (int b = 0; b < NB; ++b) {
                uint32_t rem = k - taken;
                uint32_t c = h[b];
                uint32_t t = c < rem ? c : rem;
                bsum += (float)t * (((float)b + 0.5f) * BINW);
                taken += t;
            }
            if (taken < k) bsum += (float)(k - taken) * LOWR;
            float B = (k > 0) ? (bsum / (float)k) : 0.0f;
            wsf[WS_DSEG + s*4 + 0] = s_acc[10 + s] / fn - B;
            wsf[WS_DSEG + s*4 + 1] = s_acc[20 + s] / fn - B;
            wsf[WS_DSEG + s*4 + 2] = s_acc[30 + s] / fn - B;
            wsf[WS_DSEG + s*4 + 3] = 0.0f;
        } else if (s == NSEG) {
            wsf[WS_DSEG + 40] = 0.0f; wsf[WS_DSEG + 41] = 0.0f;
            wsf[WS_DSEG + 42] = 0.0f; wsf[WS_DSEG + 43] = 0.0f;
        }
    }
    grid.sync();                               // s4

    // ---- P5: 3x3 depth-guided smoothing; depth+dval slices L2-hot ----
    {
        if (threadIdx.x < NSEG+1)
            s_D4[threadIdx.x] = ((const float4*)(wsf + WS_DSEG))[threadIdx.x];
        __syncthreads();
        int lane = threadIdx.x & 63;
        for (int g = tid; g < HWPX/4; g += NTH) {
            int row = g >> 9;                  // uniform per wave
            int col = (g & 511) << 2;

            float4 dva4 = ((const float4*)(wsf + WS_DVAL))[g];

            float nd[3][6];
            #pragma unroll
            for (int rr = 0; rr < 3; ++rr) {
                int r2 = row + rr - 1;
                if (r2 >= 0 && r2 < HH) {      // wave-uniform branch
                    const float* dp = depth + (size_t)r2 * WW + col;
                    float4 m = *(const float4*)dp;
                    float left  = __shfl_up(m.w, 1, 64);
                    float right = __shfl_down(m.x, 1, 64);
                    if (lane == 0)  left  = (col > 0)      ? dp[-1] : INFINITY;
                    if (lane == 63) right = (col + 4 < WW) ? dp[4]  : INFINITY;
                    nd[rr][0] = left;  nd[rr][1] = m.x; nd[rr][2] = m.y;
                    nd[rr][3] = m.z;   nd[rr][4] = m.w; nd[rr][5] = right;
                } else {
                    #pragma unroll
                    for (int cc = 0; cc < 6; ++cc) nd[rr][cc] = INFINITY;
                }
            }

            float cnt[4], A0[4], A1[4], A2[4];
            #pragma unroll
            for (int j = 0; j < 4; ++j) { cnt[j]=0.f; A0[j]=0.f; A1[j]=0.f; A2[j]=0.f; }

            #pragma unroll
            for (int rr = 0; rr < 3; ++rr) {
                #pragma unroll
                for (int cc = 0; cc < 6; ++cc) {
                    float nv = nd[rr][cc];
                    float4 dd = s_D4[seg_of(nv, dmin, dmax, invw)];
                    #pragma unroll
                    for (int j = 0; j < 4; ++j) {
                        if (j >= cc - 2 && j <= cc) {      // compile-time folded
                            float msk = (fabsf(nv - nd[1][j+1]) < 1.0f) ? 1.0f : 0.0f;
                            cnt[j] += msk; A0[j] += msk*dd.x; A1[j] += msk*dd.y; A2[j] += msk*dd.z;
                        }
                    }
                }
            }

            float dva[4] = {dva4.x, dva4.y, dva4.z, dva4.w};
            float o0[4], o1[4], o2[4];
            #pragma unroll
            for (int j = 0; j < 4; ++j) {
                float rc = 1.0f / cnt[j];
                float4 Dc = s_D4[seg_of(nd[1][j+1], dmin, dmax, invw)];
                // E = F_SCALE*(P_MIX*D + (1-P_MIX)*a') = D + a'; J = E*d
                o0[j] = (Dc.x + A0[j]*rc) * dva[j];
                o1[j] = (Dc.y + A1[j]*rc) * dva[j];
                o2[j] = (Dc.z + A2[j]*rc) * dva[j];
            }
            size_t base = (size_t)row * WW + col;
            vfloat4 v0 = {o0[0], o0[1], o0[2], o0[3]};
            vfloat4 v1 = {o1[0], o1[1], o1[2], o1[3]};
            vfloat4 v2 = {o2[0], o2[1], o2[2], o2[3]};
            __builtin_nontemporal_store(v0, (vfloat4*)(out + base));
            __builtin_nontemporal_store(v1, (vfloat4*)(out + HWPX + base));
            __builtin_nontemporal_store(v2, (vfloat4*)(out + 2*HWPX + base));
        }
    }
}

// ===========================================================================
// Fallback path: the verified 5-kernel chain (used only if cooperative launch
// is rejected, e.g. by graph capture). Bodies identical to the prior kernel.
// ===========================================================================
__global__ __launch_bounds__(256) void k1_minmax(const float* __restrict__ depth,
                                                 float* __restrict__ wsf) {
    int tid = blockIdx.x * 256 + threadIdx.x;
    float vmin = INFINITY, vmax = 0.0f;
    const float4* d4 = (const float4*)depth;
    for (int i = tid; i < HWPX/4; i += NTH) {
        float4 v = d4[i];
        vmin = fminf(vmin, fminf(fminf(v.x, v.y), fminf(v.z, v.w)));
        vmax = fmaxf(vmax, fmaxf(fmaxf(v.x, v.y), fmaxf(v.z, v.w)));
    }
    #pragma unroll
    for (int off = 32; off > 0; off >>= 1) {
        vmin = fminf(vmin, __shfl_down(vmin, off, 64));
        vmax = fmaxf(vmax, __shfl_down(vmax, off, 64));
    }
    __shared__ float smin[4], smax[4];
    int wid = threadIdx.x >> 6;
    if ((threadIdx.x & 63) == 0) { smin[wid] = vmin; smax[wid] = vmax; }
    __syncthreads();
    if (threadIdx.x == 0) {
        wsf[WS_BMM + blockIdx.x]        = fminf(fminf(smin[0], smin[1]), fminf(smin[2], smin[3]));
        wsf[WS_BMM + NBLK + blockIdx.x] = fmaxf(fmaxf(smax[0], smax[1]), fmaxf(smax[2], smax[3]));
    }
}

__global__ __launch_bounds__(256, 2) void k2_hist(const float* __restrict__ image,
                                                  const float* __restrict__ depth,
                                                  const float* __restrict__ mu0p,
                                                  const float* __restrict__ mu1p,
                                                  const float* __restrict__ mu2p,
                                                  uint32_t* __restrict__ wsu) {
    __shared__ uint32_t s_hist[HIST_WORDS];
    __shared__ float s_red[4][40];
    __shared__ float smn[4], smx[4];
    float* wsf = (float*)wsu;
    for (int j = threadIdx.x; j < HIST_WORDS; j += 256) s_hist[j] = 0;

    float dmin, dmax;
    block_minmax(wsf, dmin, dmax, smn, smx);
    float invw = 10.0f / (dmax - dmin);
    float mu0 = *mu0p, mu1 = *mu1p, mu2 = *mu2p;

    float c_cnt[NSEG], c_r[NSEG], c_g[NSEG], c_b[NSEG];
    #pragma unroll
    for (int s = 0; s < NSEG; ++s) { c_cnt[s]=0.f; c_r[s]=0.f; c_g[s]=0.f; c_b[s]=0.f; }

    const float4* r4 = (const float4*)image;
    const float4* g4 = (const float4*)(image + HWPX);
    const float4* b4 = (const float4*)(image + 2*HWPX);
    const float4* d4 = (const float4*)depth;
    vfloat4* dval4 = (vfloat4*)(wsf + WS_DVAL);
    int tid = blockIdx.x * 256 + threadIdx.x;
    for (int i = tid; i < HWPX/4; i += NTH) {
        float4 rv = r4[i], gv = g4[i], bv = b4[i], dv = d4[i];
        float ra[4] = {rv.x, rv.y, rv.z, rv.w};
        float ga[4] = {gv.x, gv.y, gv.z, gv.w};
        float ba[4] = {bv.x, bv.y, bv.z, bv.w};
        float da[4] = {dv.x, dv.y, dv.z, dv.w};
        float dvo[4];
        #pragma unroll
        for (int j = 0; j < 4; ++j) {
            int sg = seg_of(da[j], dmin, dmax, invw);
            float m = fminf(ra[j], fminf(ga[j], ba[j]));
            if (sg < NSEG && m < LOWR) {
                atomicAdd(&s_hist[sg*NB + (int)(m * INV_LOWW)], 1u);
            }
            #pragma unroll
            for (int s = 0; s < NSEG; ++s) {
                float sel = (sg == s) ? 1.0f : 0.0f;
                c_cnt[s] += sel;
                c_r[s] += sel * ra[j];
                c_g[s] += sel * ga[j];
                c_b[s] += sel * ba[j];
            }
            dvo[j] = mu0 + mu1 * fmaxf(ga[j], ba[j]) + mu2 * ra[j];
        }
        vfloat4 dq = {dvo[0], dvo[1], dvo[2], dvo[3]};
        dval4[i] = dq;
    }
    #pragma unroll
    for (int s = 0; s < NSEG; ++s) {
        #pragma unroll
        for (int off = 32; off > 0; off >>= 1) {
            c_cnt[s] += __shfl_down(c_cnt[s], off, 64);
            c_r[s]   += __shfl_down(c_r[s],   off, 64);
            c_g[s]   += __shfl_down(c_g[s],   off, 64);
            c_b[s]   += __shfl_down(c_b[s],   off, 64);
        }
    }
    int wid = threadIdx.x >> 6;
    if ((threadIdx.x & 63) == 0) {
        #pragma unroll
        for (int s = 0; s < NSEG; ++s) {
            s_red[wid][s]      = c_cnt[s];
            s_red[wid][10 + s] = c_r[s];
            s_red[wid][20 + s] = c_g[s];
            s_red[wid][30 + s] = c_b[s];
        }
    }
    __syncthreads();
    uint32_t* slice = wsu + WS_SLICE + (size_t)blockIdx.x * SLICE_W;
    for (int j = threadIdx.x; j < HIST_WORDS; j += 256)
        __builtin_nontemporal_store(s_hist[j], &slice[j]);
    if (threadIdx.x < 40) {
        float v = s_red[0][threadIdx.x] + s_red[1][threadIdx.x]
                + s_red[2][threadIdx.x] + s_red[3][threadIdx.x];
        __builtin_nontemporal_store(v, &((float*)slice)[HIST_WORDS + threadIdx.x]);
    }
}

__global__ __launch_bounds__(256) void k3a_reduce(uint32_t* __restrict__ wsu) {
    int j = blockIdx.x * 256 + threadIdx.x;
    if (j >= SLICE_W) return;
    int y = blockIdx.y;
    const uint32_t* p = wsu + WS_SLICE + (size_t)(y * (NBLK/NPART)) * SLICE_W + j;
    if (j < HIST_WORDS) {
        uint32_t acc = 0;
        #pragma unroll 4
        for (int b = 0; b < NBLK/NPART; ++b) acc += p[(size_t)b * SLICE_W];
        wsu[WS_PART + y*SLICE_W + j] = acc;
    } else {
        float acc = 0.0f;
        #pragma unroll 4
        for (int b = 0; b < NBLK/NPART; ++b) acc += ((const float*)p)[(size_t)b * SLICE_W];
        ((float*)wsu)[WS_PART + y*SLICE_W + j] = acc;
    }
}

__global__ void k3b_stats(uint32_t* __restrict__ wsu) {
    __shared__ uint32_t s_hist[HIST_WORDS];
    __shared__ float s_acc[40];
    __shared__ float smn[4], smx[4];
    float* wsf = (float*)wsu;
    for (int j = threadIdx.x; j < SLICE_W; j += 256) {
        if (j < HIST_WORDS) {
            uint32_t acc = 0;
            #pragma unroll
            for (int y = 0; y < NPART; ++y) acc += wsu[WS_PART + y*SLICE_W + j];
            s_hist[j] = acc;
        } else {
            float acc = 0.0f;
            #pragma unroll
            for (int y = 0; y < NPART; ++y) acc += wsf[WS_PART + y*SLICE_W + j];
            s_acc[j - HIST_WORDS] = acc;
        }
    }
    float dmin, dmax;
    block_minmax(wsf, dmin, dmax, smn, smx);
    int s = threadIdx.x;
    if (s < NSEG) {
        float fn = s_acc[s];
        uint32_t n = (uint32_t)(fn + 0.5f);
        uint32_t k = n / 100;
        const uint32_t* h = &s_hist[s*NB];
        float bsum = 0.0f; uint32_t taken = 0;
        for (int b = 0; b < NB; ++b) {
            uint32_t rem = k - taken;
            uint32_t c = h[b];
            uint32_t t = c < rem ? c : rem;
            bsum += (float)t * (((float)b + 0.5f) * BINW);
            taken += t;
        }
        if (taken < k) bsum += (float)(k - taken) * LOWR;
        float B = (k > 0) ? (bsum / (float)k) : 0.0f;
        wsf[WS_DSEG + s*4 + 0] = s_acc[10 + s] / fn - B;
        wsf[WS_DSEG + s*4 + 1] = s_acc[20 + s] / fn - B;
        wsf[WS_DSEG + s*4 + 2] = s_acc[30 + s] / fn - B;
        wsf[WS_DSEG + s*4 + 3] = 0.0f;
    } else if (s == NSEG) {
        wsf[WS_DSEG + 40] = 0.0f; wsf[WS_DSEG + 41] = 0.0f;
        wsf[WS_DSEG + 42] = 0.0f; wsf[WS_DSEG + 43] = 0.0f;
    } else if (s == NSEG+1) {
        wsf[WS_DMM] = dmin; wsf[WS_DMM + 1] = dmax;
    }
}

__global__ __launch_bounds__(256, 2) void k4_out(const float* __restrict__ depth,
                                                 const uint32_t* __restrict__ wsu,
                                                 float* __restrict__ out) {
    __shared__ float4 s_D4[NSEG+1];
    const float* wsf = (const float*)wsu;
    if (threadIdx.x < NSEG+1)
        s_D4[threadIdx.x] = ((const float4*)(wsf + WS_DSEG))[threadIdx.x];
    __syncthreads();

    float dmin = wsf[WS_DMM];
    float dmax = wsf[WS_DMM + 1];
    float invw = 10.0f / (dmax - dmin);

    int gid = blockIdx.x * 256 + threadIdx.x;
    int row = gid >> 9;
    int col = (gid & 511) << 2;
    int lane = threadIdx.x & 63;

    float4 dva4 = ((const float4*)(wsf + WS_DVAL))[gid];

    float nd[3][6];
    #pragma unroll
    for (int rr = 0; rr < 3; ++rr) {
        int r2 = row + rr - 1;
        if (r2 >= 0 && r2 < HH) {
            const float* dp = depth + (size_t)r2 * WW + col;
            float4 m = *(const float4*)dp;
            float left  = __shfl_up(m.w, 1, 64);
            float right = __shfl_down(m.x, 1, 64);
            if (lane == 0)  left  = (col > 0)      ? dp[-1] : INFINITY;
            if (lane == 63) right = (col + 4 < WW) ? dp[4]  : INFINITY;
            nd[rr][0] = left;  nd[rr][1] = m.x; nd[rr][2] = m.y;
            nd[rr][3] = m.z;   nd[rr][4] = m.w; nd[rr][5] = right;
        } else {
            #pragma unroll
            for (int cc = 0; cc < 6; ++cc) nd[rr][cc] = INFINITY;
        }
    }

    float cnt[4], A0[4], A1[4], A2[4];
    #pragma unroll
    for (int j = 0; j < 4; ++j) { cnt[j]=0.f; A0[j]=0.f; A1[j]=0.f; A2[j]=0.f; }

    #pragma unroll
    for (int rr = 0; rr < 3; ++rr) {
        #pragma unroll
        for (int cc = 0; cc < 6; ++cc) {
            float nv = nd[rr][cc];
            float4 dd = s_D4[seg_of(nv, dmin, dmax, invw)];
            #pragma unroll
            for (int j = 0; j < 4; ++j) {
                if (j >= cc - 2 && j <= cc) {
                    float msk = (fabsf(nv - nd[1][j+1]) < 1.0f) ? 1.0f : 0.0f;
                    cnt[j] += msk; A0[j] += msk*dd.x; A1[j] += msk*dd.y; A2[j] += msk*dd.z;
                }
            }
        }
    }

    float dva[4] = {dva4.x, dva4.y, dva4.z, dva4.w};
    float o0[4], o1[4], o2[4];
    #pragma unroll
    for (int j = 0; j < 4; ++j) {
        float rc = 1.0f / cnt[j];
        float4 Dc = s_D4[seg_of(nd[1][j+1], dmin, dmax, invw)];
        o0[j] = (Dc.x + A0[j]*rc) * dva[j];
        o1[j] = (Dc.y + A1[j]*rc) * dva[j];
        o2[j] = (Dc.z + A2[j]*rc) * dva[j];
    }
    size_t base = (size_t)row * WW + col;
    vfloat4 v0 = {o0[0], o0[1], o0[2], o0[3]};
    vfloat4 v1 = {o1[0], o1[1], o1[2], o1[3]};
    vfloat4 v2 = {o2[0], o2[1], o2[2], o2[3]};
    __builtin_nontemporal_store(v0, (vfloat4*)(out + base));
    __builtin_nontemporal_store(v1, (vfloat4*)(out + HWPX + base));
    __builtin_nontemporal_store(v2, (vfloat4*)(out + 2*HWPX + base));
}

extern "C" void kernel_launch(void* const* d_in, const int* in_sizes, int n_in,
                              void* d_out, int out_size, void* d_ws, size_t ws_size,
                              hipStream_t stream) {
    const float* image = (const float*)d_in[0];
    const float* depth = (const float*)d_in[1];
    const float* mu0   = (const float*)d_in[2];
    const float* mu1   = (const float*)d_in[3];
    const float* mu2   = (const float*)d_in[4];
    uint32_t* wsu = (uint32_t*)d_ws;
    float* out = (float*)d_out;

    void* args[7];
    args[0] = (void*)&image; args[1] = (void*)&depth;
    args[2] = (void*)&mu0;   args[3] = (void*)&mu1;   args[4] = (void*)&mu2;
    args[5] = (void*)&wsu;   args[6] = (void*)&out;
    hipError_t err = hipLaunchCooperativeKernel((void*)fused_eigm, dim3(NBLK), dim3(NTHR),
                                                args, 0, stream);
    if (err != hipSuccess) {
        // Cooperative launch unavailable (e.g. graph-capture rejection):
        // fall back to the verified 5-kernel chain.
        hipLaunchKernelGGL(k1_minmax,  dim3(NBLK), dim3(256), 0, stream, depth, (float*)wsu);
        hipLaunchKernelGGL(k2_hist,    dim3(NBLK), dim3(256), 0, stream,
                           image, depth, mu0, mu1, mu2, wsu);
        hipLaunchKernelGGL(k3a_reduce, dim3(6, NPART), dim3(256), 0, stream, wsu);
        hipLaunchKernelGGL(k3b_stats,  dim3(1),        dim3(256), 0, stream, wsu);
        hipLaunchKernelGGL(k4_out,     dim3((HWPX/4)/256), dim3(256), 0, stream,
                           depth, wsu, out);
    }
}

// Round 3
// 159.132 us; speedup vs baseline: 2.3841x; 2.3841x over previous
//
#include <hip/hip_runtime.h>
#include <cstdint>
#include <math.h>

#define HH 2048
#define WW 2048
#define HWPX (HH*WW)
#define NSEG 10
#define NB 128
#define HIST_WORDS (NSEG*NB)       // 1280
#define LOWR 0.03125f
#define INV_LOWW 4096.0f           // NB / LOWR
#define BINW (LOWR/(float)NB)      // 2.441e-4

#define K1_BLOCKS 512
#define K2_BLOCKS 512              // FROZEN: phase-2 accumulation order (bit-exact absmax)
#define NTH (K2_BLOCKS*256)        // 131072 threads; HWPX/4 / NTH = 8 iters exactly
#define SLICE_W 1320               // 1280 hist + 40 acc per block
#define NPART 16                   // k3a reduction fan-in stage (512/16 = 32 slices each)

typedef float vfloat4 __attribute__((ext_vector_type(4)));

// workspace layout (32-bit words) — no init kernel: everything is written with
// plain stores before it is read (harness 0xAA poison is harmless).
#define WS_BMM 0                            // 1024: k1 per-block min[512], max[512]
#define WS_PART 1024                        // NPART * SLICE_W = 21120 partials
#define WS_DSEG 22144                       // 16B-aligned: 11 float4 (seg 10 = zeros)
#define WS_DMM (WS_DSEG + 44)               // dmin, dmax (published by k3b for k4)
#define WS_DVAL 22192                       // HWPX floats: dval staged k2 -> k4 (16.8 MB)
#define WS_SLICE (WS_DVAL + HWPX)           // K2_BLOCKS * SLICE_W (2.7 MB)

// Segment rule: replicates bins = linspace(dmin,dmax,11); pixel in seg s iff
// bins[s] <= v < bins[s+1]. v == dmax (== bins[10]) is in NO segment -> 10.
__device__ __forceinline__ int seg_of(float v, float dmin, float dmax, float invw) {
    int sg = (int)((v - dmin) * invw);
    sg = sg > (NSEG-1) ? (NSEG-1) : sg;
    return (v >= dmax) ? NSEG : sg;
}

// k1: per-block depth min/max -> plain stores (no atomics, no init required)
__global__ __launch_bounds__(256) void k1_minmax(const float* __restrict__ depth,
                                                 float* __restrict__ wsf) {
    int tid = blockIdx.x * 256 + threadIdx.x;
    float vmin = INFINITY, vmax = 0.0f;
    const float4* d4 = (const float4*)depth;
    for (int i = tid; i < HWPX/4; i += NTH) {
        float4 v = d4[i];
        vmin = fminf(vmin, fminf(fminf(v.x, v.y), fminf(v.z, v.w)));
        vmax = fmaxf(vmax, fmaxf(fmaxf(v.x, v.y), fmaxf(v.z, v.w)));
    }
    #pragma unroll
    for (int off = 32; off > 0; off >>= 1) {
        vmin = fminf(vmin, __shfl_down(vmin, off, 64));
        vmax = fmaxf(vmax, __shfl_down(vmax, off, 64));
    }
    __shared__ float smin[4], smax[4];
    int wid = threadIdx.x >> 6;
    if ((threadIdx.x & 63) == 0) { smin[wid] = vmin; smax[wid] = vmax; }
    __syncthreads();
    if (threadIdx.x == 0) {
        wsf[WS_BMM + blockIdx.x]             = fminf(fminf(smin[0], smin[1]), fminf(smin[2], smin[3]));
        wsf[WS_BMM + K1_BLOCKS + blockIdx.x] = fmaxf(fmaxf(smax[0], smax[1]), fmaxf(smax[2], smax[3]));
    }
}

// Each block re-reduces k1's 512+512 per-block values (4 KB, L2/L3-hot).
__device__ __forceinline__ void block_minmax(const float* wsf, float& dmin, float& dmax,
                                             float smn[4], float smx[4]) {
    float v0 = fminf(wsf[WS_BMM + threadIdx.x], wsf[WS_BMM + 256 + threadIdx.x]);
    float v1 = fmaxf(wsf[WS_BMM + K1_BLOCKS + threadIdx.x],
                     wsf[WS_BMM + K1_BLOCKS + 256 + threadIdx.x]);
    #pragma unroll
    for (int off = 32; off > 0; off >>= 1) {
        v0 = fminf(v0, __shfl_down(v0, off, 64));
        v1 = fmaxf(v1, __shfl_down(v1, off, 64));
    }
    int wid = threadIdx.x >> 6;
    if ((threadIdx.x & 63) == 0) { smn[wid] = v0; smx[wid] = v1; }
    __syncthreads();
    dmin = fminf(fminf(smn[0], smn[1]), fminf(smn[2], smn[3]));
    dmax = fmaxf(fmaxf(smx[0], smx[1]), fmaxf(smx[2], smx[3]));
}

// k2: register per-seg stats; LDS hist only for m < LOWR (~9%); dval staged to
// ws for k4. Software-pipelined (prefetch-1): k2 runs at only 2 blocks/CU
// (grid frozen by reduction order), so latency hiding must come from ILP.
// Image loads nontemporal (streamed once; don't evict depth/dval from L2).
// dval store nontemporal (consumed only by k4, via L3).
__global__ __launch_bounds__(256, 2) void k2_hist(const float* __restrict__ image,
                                                  const float* __restrict__ depth,
                                                  const float* __restrict__ mu0p,
                                                  const float* __restrict__ mu1p,
                                                  const float* __restrict__ mu2p,
                                                  uint32_t* __restrict__ wsu) {
    __shared__ uint32_t s_hist[HIST_WORDS];
    __shared__ float s_red[4][40];
    __shared__ float smn[4], smx[4];
    float* wsf = (float*)wsu;
    for (int j = threadIdx.x; j < HIST_WORDS; j += 256) s_hist[j] = 0;

    float dmin, dmax;
    block_minmax(wsf, dmin, dmax, smn, smx);       // includes the needed __syncthreads
    float invw = 10.0f / (dmax - dmin);
    float mu0 = *mu0p, mu1 = *mu1p, mu2 = *mu2p;

    float c_cnt[NSEG], c_r[NSEG], c_g[NSEG], c_b[NSEG];
    #pragma unroll
    for (int s = 0; s < NSEG; ++s) { c_cnt[s]=0.f; c_r[s]=0.f; c_g[s]=0.f; c_b[s]=0.f; }

    const vfloat4* r4 = (const vfloat4*)image;
    const vfloat4* g4 = (const vfloat4*)(image + HWPX);
    const vfloat4* b4 = (const vfloat4*)(image + 2*HWPX);
    const vfloat4* d4 = (const vfloat4*)depth;
    vfloat4* dval4 = (vfloat4*)(wsf + WS_DVAL);
    int tid = blockIdx.x * 256 + threadIdx.x;

    // prologue: load iteration 0
    int i = tid;
    vfloat4 rv = __builtin_nontemporal_load(&r4[i]);
    vfloat4 gv = __builtin_nontemporal_load(&g4[i]);
    vfloat4 bv = __builtin_nontemporal_load(&b4[i]);
    vfloat4 dv = d4[i];

    while (i < HWPX/4) {
        int inext = i + NTH;
        vfloat4 rn, gn, bn, dn;
        bool more = inext < HWPX/4;
        if (more) {                                 // prefetch next iteration
            rn = __builtin_nontemporal_load(&r4[inext]);
            gn = __builtin_nontemporal_load(&g4[inext]);
            bn = __builtin_nontemporal_load(&b4[inext]);
            dn = d4[inext];
        }
        float ra[4] = {rv.x, rv.y, rv.z, rv.w};
        float ga[4] = {gv.x, gv.y, gv.z, gv.w};
        float ba[4] = {bv.x, bv.y, bv.z, bv.w};
        float da[4] = {dv.x, dv.y, dv.z, dv.w};
        float dvo[4];
        #pragma unroll
        for (int j = 0; j < 4; ++j) {
            int sg = seg_of(da[j], dmin, dmax, invw);
            float m = fminf(ra[j], fminf(ga[j], ba[j]));
            if (sg < NSEG && m < LOWR) {
                atomicAdd(&s_hist[sg*NB + (int)(m * INV_LOWW)], 1u);
            }
            #pragma unroll
            for (int s = 0; s < NSEG; ++s) {
                float sel = (sg == s) ? 1.0f : 0.0f;
                c_cnt[s] += sel;
                c_r[s] += sel * ra[j];
                c_g[s] += sel * ga[j];
                c_b[s] += sel * ba[j];
            }
            dvo[j] = mu0 + mu1 * fmaxf(ga[j], ba[j]) + mu2 * ra[j];
        }
        vfloat4 dq = {dvo[0], dvo[1], dvo[2], dvo[3]};
        __builtin_nontemporal_store(dq, &dval4[i]);
        i = inext;
        rv = rn; gv = gn; bv = bn; dv = dn;
    }
    #pragma unroll
    for (int s = 0; s < NSEG; ++s) {
        #pragma unroll
        for (int off = 32; off > 0; off >>= 1) {
            c_cnt[s] += __shfl_down(c_cnt[s], off, 64);
            c_r[s]   += __shfl_down(c_r[s],   off, 64);
            c_g[s]   += __shfl_down(c_g[s],   off, 64);
            c_b[s]   += __shfl_down(c_b[s],   off, 64);
        }
    }
    int wid = threadIdx.x >> 6;
    if ((threadIdx.x & 63) == 0) {
        #pragma unroll
        for (int s = 0; s < NSEG; ++s) {
            s_red[wid][s]      = c_cnt[s];
            s_red[wid][10 + s] = c_r[s];
            s_red[wid][20 + s] = c_g[s];
            s_red[wid][30 + s] = c_b[s];
        }
    }
    __syncthreads();
    uint32_t* slice = wsu + WS_SLICE + (size_t)blockIdx.x * SLICE_W;
    for (int j = threadIdx.x; j < HIST_WORDS; j += 256)
        __builtin_nontemporal_store(s_hist[j], &slice[j]);
    if (threadIdx.x < 40) {
        float v = s_red[0][threadIdx.x] + s_red[1][threadIdx.x]
                + s_red[2][threadIdx.x] + s_red[3][threadIdx.x];
        __builtin_nontemporal_store(v, &((float*)slice)[HIST_WORDS + threadIdx.x]);
    }
}

// k3a: reduce K2_BLOCKS slices -> NPART partials (plain stores, no atomics/init)
__global__ __launch_bounds__(256) void k3a_reduce(uint32_t* __restrict__ wsu) {
    int j = blockIdx.x * 256 + threadIdx.x;
    if (j >= SLICE_W) return;
    int y = blockIdx.y;
    const uint32_t* p = wsu + WS_SLICE + (size_t)(y * (K2_BLOCKS/NPART)) * SLICE_W + j;
    if (j < HIST_WORDS) {
        uint32_t acc = 0;
        #pragma unroll 4
        for (int b = 0; b < K2_BLOCKS/NPART; ++b) acc += p[(size_t)b * SLICE_W];
        wsu[WS_PART + y*SLICE_W + j] = acc;
    } else {
        float acc = 0.0f;
        #pragma unroll 4
        for (int b = 0; b < K2_BLOCKS/NPART; ++b) acc += ((const float*)p)[(size_t)b * SLICE_W];
        ((float*)wsu)[WS_PART + y*SLICE_W + j] = acc;
    }
}

// k3b: final partial sum + bottom-k scan + D_seg + dmin/dmax publish (1 block)
__global__ void k3b_stats(uint32_t* __restrict__ wsu) {
    __shared__ uint32_t s_hist[HIST_WORDS];
    __shared__ float s_acc[40];
    __shared__ float smn[4], smx[4];
    float* wsf = (float*)wsu;
    for (int j = threadIdx.x; j < SLICE_W; j += 256) {
        if (j < HIST_WORDS) {
            uint32_t acc = 0;
            #pragma unroll
            for (int y = 0; y < NPART; ++y) acc += wsu[WS_PART + y*SLICE_W + j];
            s_hist[j] = acc;
        } else {
            float acc = 0.0f;
            #pragma unroll
            for (int y = 0; y < NPART; ++y) acc += wsf[WS_PART + y*SLICE_W + j];
            s_acc[j - HIST_WORDS] = acc;
        }
    }
    float dmin, dmax;
    block_minmax(wsf, dmin, dmax, smn, smx);   // syncthreads inside covers s_hist/s_acc
    int s = threadIdx.x;
    if (s < NSEG) {
        float fn = s_acc[s];                   // exact integer-valued float
        uint32_t n = (uint32_t)(fn + 0.5f);
        uint32_t k = n / 100;                  // n * BOTTOM_PCT // 100
        const uint32_t* h = &s_hist[s*NB];
        float bsum = 0.0f; uint32_t taken = 0;
        for (int b = 0; b < NB; ++b) {
            uint32_t rem = k - taken;
            uint32_t c = h[b];
            uint32_t t = c < rem ? c : rem;
            bsum += (float)t * (((float)b + 0.5f) * BINW);
            taken += t;
        }
        if (taken < k) bsum += (float)(k - taken) * LOWR;
        float B = (k > 0) ? (bsum / (float)k) : 0.0f;
        wsf[WS_DSEG + s*4 + 0] = s_acc[10 + s] / fn - B;
        wsf[WS_DSEG + s*4 + 1] = s_acc[20 + s] / fn - B;
        wsf[WS_DSEG + s*4 + 2] = s_acc[30 + s] / fn - B;
        wsf[WS_DSEG + s*4 + 3] = 0.0f;
    } else if (s == NSEG) {
        wsf[WS_DSEG + 40] = 0.0f; wsf[WS_DSEG + 41] = 0.0f;
        wsf[WS_DSEG + 42] = 0.0f; wsf[WS_DSEG + 43] = 0.0f;
    } else if (s == NSEG+1) {
        wsf[WS_DMM] = dmin; wsf[WS_DMM + 1] = dmax;
    }
}

// k4: 3x3 depth-guided smoothing; reads staged dval (image never touched).
// 4096 blocks, no ordering constraint: raise occupancy floor to 4 blocks/CU.
__global__ __launch_bounds__(256, 4) void k4_out(const float* __restrict__ depth,
                                                 const uint32_t* __restrict__ wsu,
                                                 float* __restrict__ out) {
    __shared__ float4 s_D4[NSEG+1];
    const float* wsf = (const float*)wsu;
    if (threadIdx.x < NSEG+1)
        s_D4[threadIdx.x] = ((const float4*)(wsf + WS_DSEG))[threadIdx.x];
    __syncthreads();

    float dmin = wsf[WS_DMM];
    float dmax = wsf[WS_DMM + 1];
    float invw = 10.0f / (dmax - dmin);

    int gid = blockIdx.x * 256 + threadIdx.x;       // one 4-px quad per thread
    int row = gid >> 9;                              // uniform per wave
    int col = (gid & 511) << 2;
    int lane = threadIdx.x & 63;

    float4 dva4 = ((const float4*)(wsf + WS_DVAL))[gid];

    float nd[3][6];
    #pragma unroll
    for (int rr = 0; rr < 3; ++rr) {
        int r2 = row + rr - 1;
        if (r2 >= 0 && r2 < HH) {                    // wave-uniform branch
            const float* dp = depth + (size_t)r2 * WW + col;
            float4 m = *(const float4*)dp;
            float left  = __shfl_up(m.w, 1, 64);
            float right = __shfl_down(m.x, 1, 64);
            if (lane == 0)  left  = (col > 0)      ? dp[-1] : INFINITY;
            if (lane == 63) right = (col + 4 < WW) ? dp[4]  : INFINITY;
            nd[rr][0] = left;  nd[rr][1] = m.x; nd[rr][2] = m.y;
            nd[rr][3] = m.z;   nd[rr][4] = m.w; nd[rr][5] = right;
        } else {
            #pragma unroll
            for (int cc = 0; cc < 6; ++cc) nd[rr][cc] = INFINITY;
        }
    }

    float cnt[4], A0[4], A1[4], A2[4];
    #pragma unroll
    for (int j = 0; j < 4; ++j) { cnt[j]=0.f; A0[j]=0.f; A1[j]=0.f; A2[j]=0.f; }

    #pragma unroll
    for (int rr = 0; rr < 3; ++rr) {
        #pragma unroll
        for (int cc = 0; cc < 6; ++cc) {
            float nv = nd[rr][cc];
            float4 dd = s_D4[seg_of(nv, dmin, dmax, invw)];
            #pragma unroll
            for (int j = 0; j < 4; ++j) {
                if (j >= cc - 2 && j <= cc) {        // compile-time folded
                    float msk = (fabsf(nv - nd[1][j+1]) < 1.0f) ? 1.0f : 0.0f;
                    cnt[j] += msk; A0[j] += msk*dd.x; A1[j] += msk*dd.y; A2[j] += msk*dd.z;
                }
            }
        }
    }

    float dva[4] = {dva4.x, dva4.y, dva4.z, dva4.w};
    float o0[4], o1[4], o2[4];
    #pragma unroll
    for (int j = 0; j < 4; ++j) {
        float rc = 1.0f / cnt[j];
        float4 Dc = s_D4[seg_of(nd[1][j+1], dmin, dmax, invw)];
        // E = F_SCALE*(P_MIX*D + (1-P_MIX)*a') = D + a'; J = E*d
        o0[j] = (Dc.x + A0[j]*rc) * dva[j];
        o1[j] = (Dc.y + A1[j]*rc) * dva[j];
        o2[j] = (Dc.z + A2[j]*rc) * dva[j];
    }
    size_t base = (size_t)row * WW + col;
    vfloat4 v0 = {o0[0], o0[1], o0[2], o0[3]};
    vfloat4 v1 = {o1[0], o1[1], o1[2], o1[3]};
    vfloat4 v2 = {o2[0], o2[1], o2[2], o2[3]};
    __builtin_nontemporal_store(v0, (vfloat4*)(out + base));
    __builtin_nontemporal_store(v1, (vfloat4*)(out + HWPX + base));
    __builtin_nontemporal_store(v2, (vfloat4*)(out + 2*HWPX + base));
}

extern "C" void kernel_launch(void* const* d_in, const int* in_sizes, int n_in,
                              void* d_out, int out_size, void* d_ws, size_t ws_size,
                              hipStream_t stream) {
    const float* image = (const float*)d_in[0];
    const float* depth = (const float*)d_in[1];
    const float* mu0   = (const float*)d_in[2];
    const float* mu1   = (const float*)d_in[3];
    const float* mu2   = (const float*)d_in[4];
    uint32_t* wsu = (uint32_t*)d_ws;
    float* out = (float*)d_out;

    hipLaunchKernelGGL(k1_minmax,  dim3(K1_BLOCKS), dim3(256), 0, stream, depth, (float*)wsu);
    hipLaunchKernelGGL(k2_hist,    dim3(K2_BLOCKS), dim3(256), 0, stream,
                       image, depth, mu0, mu1, mu2, wsu);
    hipLaunchKernelGGL(k3a_reduce, dim3(6, NPART),  dim3(256), 0, stream, wsu);
    hipLaunchKernelGGL(k3b_stats,  dim3(1),         dim3(256), 0, stream, wsu);
    hipLaunchKernelGGL(k4_out,     dim3((HWPX/4)/256), dim3(256), 0, stream,
                       depth, wsu, out);
}